// Round 2
// 185.735 us; speedup vs baseline: 1.1237x; 1.1237x over previous
//
#include <hip/hip_runtime.h>

#define EPS 1e-5f
#define LOG2E 1.4426950408889634f

typedef short v8s __attribute__((ext_vector_type(8)));
typedef float v4f __attribute__((ext_vector_type(4)));

__device__ inline unsigned short f2bf(float f) {
    union { float f; unsigned u; } v; v.f = f;
    unsigned r = v.u + 0x7FFFu + ((v.u >> 16) & 1u);
    return (unsigned short)(r >> 16);
}
__device__ inline unsigned pack2(float a, float b) {
    return (unsigned)f2bf(a) | ((unsigned)f2bf(b) << 16);
}

// LDS map (38,912 B -> 4 blocks/CU when VGPR<=128, else 3):
//   [0      .. 25600)  QKf  float[64][100]   rows g*8+{0..3}=Q~ (pre-scaled by simA*log2e), g*8+{4..7}=K
//   [25600  .. 38912)  Vb   ushort[64][104]  V bf16 rows g*8+c
//   phase-1 overlay: Xb ushort[96][72] @0, Wb ushort[128][72] @13824 (dead before QKf written)
//
// Phase 2 is BARRIER-FREE: wave w owns groups {2w, 2w+1}, whose QKf/Vb rows
// were written by wave w itself in the phase-1 epilogue (within-wave LDS RAW
// ordering via lgkmcnt). Score lane layout == MFMA A-fragment layout:
//   lane computes sim[row = mt*16 + (lane&15)][col = kt*32 + quad*8 + jj],
// so P packs straight into the A operand — no LDS round trip for P.
template<bool DIRECT>
__global__ __launch_bounds__(256, 3) void attn_kernel(
    const float* __restrict__ x,
    const float* __restrict__ w,
    const float* __restrict__ qkv_gamma, const float* __restrict__ qkv_beta,
    const float* __restrict__ qkv_mean,  const float* __restrict__ qkv_var,
    const float* __restrict__ sim_gamma, const float* __restrict__ sim_beta,
    const float* __restrict__ sim_mean,  const float* __restrict__ sim_var,
    const float* __restrict__ out_gamma, const float* __restrict__ out_beta,
    const float* __restrict__ out_mean,  const float* __restrict__ out_var,
    float* __restrict__ dst)
{
    __shared__ __align__(16) unsigned char smem[38912];
    float (*QKf)[100]         = (float(*)[100])smem;
    unsigned short (*Vb)[104] = (unsigned short(*)[104])(smem + 25600);
    unsigned short (*Xb)[72]  = (unsigned short(*)[72])smem;
    unsigned short (*Wb)[72]  = (unsigned short(*)[72])(smem + 13824);

    const int tid  = threadIdx.x;
    const int lane = tid & 63;
    const int wid  = tid >> 6;
    const int quad = lane >> 4;
    const int b  = blockIdx.x;          // b = nt*64 + hs
    const int nt = b >> 6;
    const int hs = b & 63;

    const float* xb = x + (size_t)nt * 393216 + (size_t)hs * 64;
    const float4* x4 = reinterpret_cast<const float4*>(xb);
    const float4* w4 = reinterpret_cast<const float4*>(w);

    // ---------------- Phase 1a: stage X, W as bf16 ----------------
    #pragma unroll
    for (int it = 0; it < 6; ++it) {
        int idx = tid + it * 256;               // 1536 float4s
        int cl = idx >> 4, v = idx & 15;
        float4 val = x4[cl * 1024 + v];
        unsigned* dx = (unsigned*)&Xb[cl][v * 4];
        dx[0] = pack2(val.x, val.y);
        dx[1] = pack2(val.z, val.w);
    }
    #pragma unroll
    for (int it = 0; it < 8; ++it) {
        int idx = tid + it * 256;               // 2048 float4s
        int r = idx >> 4, v = idx & 15;
        float4 val = w4[r * 16 + v];
        unsigned* dw = (unsigned*)&Wb[r][v * 4];
        dw[0] = pack2(val.x, val.y);
        dw[1] = pack2(val.z, val.w);
    }
    __syncthreads();

    // ---------------- Phase 1b: QKV = W @ X via MFMA ----------------
    v4f acc1[2][6];
    #pragma unroll
    for (int mi = 0; mi < 2; ++mi)
        #pragma unroll
        for (int ni = 0; ni < 6; ++ni) acc1[mi][ni] = (v4f)(0.f);

    #pragma unroll
    for (int kt = 0; kt < 2; ++kt) {
        v8s a0 = *reinterpret_cast<const v8s*>(&Wb[(wid * 2 + 0) * 16 + (lane & 15)][kt * 32 + quad * 8]);
        v8s a1 = *reinterpret_cast<const v8s*>(&Wb[(wid * 2 + 1) * 16 + (lane & 15)][kt * 32 + quad * 8]);
        #pragma unroll
        for (int ni = 0; ni < 6; ++ni) {
            v8s bfr = *reinterpret_cast<const v8s*>(&Xb[ni * 16 + (lane & 15)][kt * 32 + quad * 8]);
            acc1[0][ni] = __builtin_amdgcn_mfma_f32_16x16x32_bf16(a0, bfr, acc1[0][ni], 0, 0, 0);
            acc1[1][ni] = __builtin_amdgcn_mfma_f32_16x16x32_bf16(a1, bfr, acc1[1][ni], 0, 0, 0);
        }
    }
    __syncthreads();    // staging dead; region becomes QKf/Vb (last barrier in kernel)

    // epilogue: BN; rows r<8 of each 16 -> QKf fp32 (Q rows scaled by simA*log2e); r>=8 -> Vb bf16
    #pragma unroll
    for (int mi = 0; mi < 2; ++mi) {
        const int mt = wid * 2 + mi;            // = group g
        const float sA = sim_gamma[mt] * rsqrtf(sim_var[mt] + EPS) * LOG2E;
        #pragma unroll
        for (int reg = 0; reg < 4; ++reg) {
            int o = mt * 16 + quad * 4 + reg;
            int r = o & 15;
            float sc = qkv_gamma[o] * rsqrtf(qkv_var[o] + EPS);
            float mb = qkv_beta[o] - qkv_mean[o] * sc;
            if (r < 4) { sc *= sA; mb *= sA; }
            if (r < 8) {
                #pragma unroll
                for (int ni = 0; ni < 6; ++ni)
                    QKf[mt * 8 + r][ni * 16 + (lane & 15)] = acc1[mi][ni][reg] * sc + mb;
            } else {
                #pragma unroll
                for (int ni = 0; ni < 6; ++ni)
                    Vb[mt * 8 + (r - 8)][ni * 16 + (lane & 15)] = f2bf(acc1[mi][ni][reg] * sc + mb);
            }
        }
    }
    // NO barrier: each wave consumes only rows it just wrote.

    // ---------------- Phase 2: wave-private groups, P in registers ----------------
    const int r15 = lane & 15;

    for (int gi = 0; gi < 2; ++gi) {
        const int g = wid * 2 + gi;

        // q preload: 24 broadcast b32 reads
        float qv[4][6];
        #pragma unroll
        for (int c = 0; c < 4; ++c)
            #pragma unroll
            for (int mt = 0; mt < 6; ++mt)
                qv[c][mt] = QKf[g * 8 + c][mt * 16 + r15];

        v4f acc[6];
        float rs[6];
        #pragma unroll
        for (int mt = 0; mt < 6; ++mt) { acc[mt] = (v4f)(0.f); rs[mt] = 0.f; }

        const float* kbase = &QKf[g * 8 + 4][quad * 8];
        const unsigned short* vbase = &Vb[g * 8 + (lane & 7)][quad * 8];

        #pragma unroll
        for (int kt = 0; kt < 3; ++kt) {
            // K block for this kt: 8 b128 broadcast reads, reused across 6 m-tiles
            v4f ka[4], kb[4];
            #pragma unroll
            for (int c = 0; c < 4; ++c) {
                ka[c] = *reinterpret_cast<const v4f*>(kbase + c * 100 + kt * 32);
                kb[c] = *reinterpret_cast<const v4f*>(kbase + c * 100 + kt * 32 + 4);
            }
            v8s vf = *reinterpret_cast<const v8s*>(vbase + kt * 32);

            #pragma unroll
            for (int mt = 0; mt < 6; ++mt) {
                float s[8];
                #pragma unroll
                for (int jj = 0; jj < 4; ++jj) {
                    s[jj]     = qv[0][mt] * ka[0][jj];
                    s[jj + 4] = qv[0][mt] * kb[0][jj];
                }
                #pragma unroll
                for (int c = 1; c < 4; ++c)
                    #pragma unroll
                    for (int jj = 0; jj < 4; ++jj) {
                        s[jj]     += qv[c][mt] * ka[c][jj];
                        s[jj + 4] += qv[c][mt] * kb[c][jj];
                    }
                float e[8];
                #pragma unroll
                for (int jj = 0; jj < 8; ++jj) e[jj] = __builtin_amdgcn_exp2f(s[jj]);
                rs[mt] += ((e[0] + e[1]) + (e[2] + e[3])) + ((e[4] + e[5]) + (e[6] + e[7]));
                union { unsigned u[4]; v8s v; } pf;
                pf.u[0] = pack2(e[0], e[1]);
                pf.u[1] = pack2(e[2], e[3]);
                pf.u[2] = pack2(e[4], e[5]);
                pf.u[3] = pack2(e[6], e[7]);
                acc[mt] = __builtin_amdgcn_mfma_f32_16x16x32_bf16(pf.v, vf, acc[mt], 0, 0, 0);
            }
        }

        // row denominators: reduce across the 4 quads
        float zr[6];
        #pragma unroll
        for (int mt = 0; mt < 6; ++mt) {
            float t = rs[mt];
            t += __shfl_xor(t, 16);
            t += __shfl_xor(t, 32);
            zr[mt] = __builtin_amdgcn_rcpf(t);
        }

        const int dd = g * 8 + (r15 & 7);
        float osc = out_gamma[dd] * rsqrtf(out_var[dd] + EPS);
        float ob  = out_beta[dd] - out_mean[dd] * osc;

        #pragma unroll
        for (int mt = 0; mt < 6; ++mt) {
            float zz[4];
            #pragma unroll
            for (int reg = 0; reg < 4; ++reg)         // all lanes active for shfl
                zz[reg] = __shfl(zr[mt], quad * 4 + reg);
            if (r15 < 8) {
                float4 o4;
                o4.x = acc[mt][0] * (zz[0] * osc) + ob;
                o4.y = acc[mt][1] * (zz[1] * osc) + ob;
                o4.z = acc[mt][2] * (zz[2] * osc) + ob;
                o4.w = acc[mt][3] * (zz[3] * osc) + ob;
                if (DIRECT) {
                    const size_t base = (size_t)nt * 393216 + (size_t)dd * 64 + hs;
                    dst[base + (size_t)(mt * 16 + quad * 4 + 0) * 4096] = o4.x;
                    dst[base + (size_t)(mt * 16 + quad * 4 + 1) * 4096] = o4.y;
                    dst[base + (size_t)(mt * 16 + quad * 4 + 2) * 4096] = o4.z;
                    dst[base + (size_t)(mt * 16 + quad * 4 + 3) * 4096] = o4.w;
                } else {
                    // ws[b][dd][i]: 8 x 64B segments per instruction (quads share lines)
                    reinterpret_cast<float4*>(dst)[(size_t)b * 1536 + dd * 24 + mt * 4 + quad] = o4;
                }
            }
        }
    }
}

// ws (nt, hs, D, cl) -> out (nt, cl, D, hs); block = (nt, D); 2048 blocks, 24.8 KB LDS -> 6 blocks/CU
__global__ __launch_bounds__(256) void transpose_kernel(const float* __restrict__ ws,
                                                        float* __restrict__ out)
{
    __shared__ float tile[64][97];
    const int blk = blockIdx.x;          // nt*64 + D
    const int nt = blk >> 6, D = blk & 63;
    const float4* ws4 = reinterpret_cast<const float4*>(ws);
    v4f* out4 = reinterpret_cast<v4f*>(out);

    #pragma unroll
    for (int it = 0; it < 6; ++it) {
        int idx = threadIdx.x + it * 256;       // 1536 float4s = 64 hs x 24 c4
        int hsr = idx / 24, c4 = idx - hsr * 24;
        float4 v = ws4[(size_t)nt * 98304 + (size_t)hsr * 1536 + D * 24 + c4];
        tile[hsr][c4 * 4 + 0] = v.x;
        tile[hsr][c4 * 4 + 1] = v.y;
        tile[hsr][c4 * 4 + 2] = v.z;
        tile[hsr][c4 * 4 + 3] = v.w;
    }
    __syncthreads();

    #pragma unroll
    for (int it = 0; it < 6; ++it) {
        int idx = threadIdx.x + it * 256;       // 1536 float4s = 96 cl x 16 h4
        int cl = idx >> 4, h4 = idx & 15;
        v4f v;
        v[0] = tile[h4 * 4 + 0][cl];
        v[1] = tile[h4 * 4 + 1][cl];
        v[2] = tile[h4 * 4 + 2][cl];
        v[3] = tile[h4 * 4 + 3][cl];
        __builtin_nontemporal_store(v, &out4[(size_t)nt * 98304 + (size_t)cl * 1024 + D * 16 + h4]);
    }
}

extern "C" void kernel_launch(void* const* d_in, const int* in_sizes, int n_in,
                              void* d_out, int out_size, void* d_ws, size_t ws_size,
                              hipStream_t stream) {
    const float* x         = (const float*)d_in[0];
    const float* w_qkv     = (const float*)d_in[1];
    const float* qkv_gamma = (const float*)d_in[2];
    const float* qkv_beta  = (const float*)d_in[3];
    const float* qkv_mean  = (const float*)d_in[4];
    const float* qkv_var   = (const float*)d_in[5];
    const float* sim_gamma = (const float*)d_in[6];
    const float* sim_beta  = (const float*)d_in[7];
    const float* sim_mean  = (const float*)d_in[8];
    const float* sim_var   = (const float*)d_in[9];
    const float* out_gamma = (const float*)d_in[10];
    const float* out_beta  = (const float*)d_in[11];
    const float* out_mean  = (const float*)d_in[12];
    const float* out_var   = (const float*)d_in[13];
    float* out = (float*)d_out;

    const size_t ws_need = (size_t)2048 * 6144 * sizeof(float);  // 50.3 MB

    if (ws_size >= ws_need) {
        float* wsb = (float*)d_ws;
        attn_kernel<false><<<2048, 256, 0, stream>>>(
            x, w_qkv, qkv_gamma, qkv_beta, qkv_mean, qkv_var,
            sim_gamma, sim_beta, sim_mean, sim_var,
            out_gamma, out_beta, out_mean, out_var, wsb);
        transpose_kernel<<<2048, 256, 0, stream>>>(wsb, out);
    } else {
        attn_kernel<true><<<2048, 256, 0, stream>>>(
            x, w_qkv, qkv_gamma, qkv_beta, qkv_mean, qkv_var,
            sim_gamma, sim_beta, sim_mean, sim_var,
            out_gamma, out_beta, out_mean, out_var, out);
    }
}

// Round 4
// 166.949 us; speedup vs baseline: 1.2502x; 1.1125x over previous
//
#include <hip/hip_runtime.h>

#define EPS 1e-5f
#define LOG2E 1.4426950408889634f

typedef short v8s __attribute__((ext_vector_type(8)));
typedef float v4f __attribute__((ext_vector_type(4)));

// RNE f32->bf16 pair pack: single instruction, HW-verified pattern (learn_hip m240/T12)
__device__ inline unsigned cvt_pk_bf16(float a, float b) {
    unsigned r;
    asm("v_cvt_pk_bf16_f32 %0, %1, %2" : "=v"(r) : "v"(a), "v"(b));
    return r;
}
__device__ inline unsigned short f2bf(float f) {
    return (unsigned short)cvt_pk_bf16(f, f);
}

// LDS map (38,912 B -> 4 blocks/CU):
//   [0      .. 25600)  QKf  float[64][100]   rows g*8+{0..3}=Q~ (pre-scaled by simA*log2e), g*8+{4..7}=K
//   [25600  .. 38912)  Vb   ushort[64][104]  V bf16 rows g*8+c
//   phase-1 overlay: Xb ushort[96][72] @0, Wb ushort[128][72] @13824 (dead before QKf written)
//
// Phase 2 is BARRIER-FREE: wave w owns groups {2w, 2w+1}, whose QKf/Vb rows
// were written by wave w itself in the phase-1 epilogue. Score lane layout ==
// MFMA A-fragment layout, so P never leaves registers.
template<bool DIRECT>
__global__ __launch_bounds__(256, 3) void attn_kernel(
    const float* __restrict__ x,
    const float* __restrict__ w,
    const float* __restrict__ qkv_gamma, const float* __restrict__ qkv_beta,
    const float* __restrict__ qkv_mean,  const float* __restrict__ qkv_var,
    const float* __restrict__ sim_gamma, const float* __restrict__ sim_beta,
    const float* __restrict__ sim_mean,  const float* __restrict__ sim_var,
    const float* __restrict__ out_gamma, const float* __restrict__ out_beta,
    const float* __restrict__ out_mean,  const float* __restrict__ out_var,
    float* __restrict__ dst)
{
    __shared__ __align__(16) unsigned char smem[38912];
    float (*QKf)[100]         = (float(*)[100])smem;
    unsigned short (*Vb)[104] = (unsigned short(*)[104])(smem + 25600);
    unsigned short (*Xb)[72]  = (unsigned short(*)[72])smem;
    unsigned short (*Wb)[72]  = (unsigned short(*)[72])(smem + 13824);

    const int tid  = threadIdx.x;
    const int lane = tid & 63;
    const int wid  = tid >> 6;
    const int quad = lane >> 4;
    const int b  = blockIdx.x;          // b = nt*64 + hs
    const int nt = b >> 6;
    const int hs = b & 63;

    const float* xb = x + (size_t)nt * 393216 + (size_t)hs * 64;
    const float4* x4 = reinterpret_cast<const float4*>(xb);
    const float4* w4 = reinterpret_cast<const float4*>(w);

    // ---------------- Phase 1a: stage X, W as bf16 ----------------
    #pragma unroll
    for (int it = 0; it < 6; ++it) {
        int idx = tid + it * 256;               // 1536 float4s
        int cl = idx >> 4, v = idx & 15;
        float4 val = x4[cl * 1024 + v];
        unsigned* dx = (unsigned*)&Xb[cl][v * 4];
        dx[0] = cvt_pk_bf16(val.x, val.y);
        dx[1] = cvt_pk_bf16(val.z, val.w);
    }
    #pragma unroll
    for (int it = 0; it < 8; ++it) {
        int idx = tid + it * 256;               // 2048 float4s
        int r = idx >> 4, v = idx & 15;
        float4 val = w4[r * 16 + v];
        unsigned* dw = (unsigned*)&Wb[r][v * 4];
        dw[0] = cvt_pk_bf16(val.x, val.y);
        dw[1] = cvt_pk_bf16(val.z, val.w);
    }
    __syncthreads();

    // ---------------- Phase 1b: QKV = W @ X via MFMA ----------------
    v4f acc1[2][6];
    #pragma unroll
    for (int mi = 0; mi < 2; ++mi)
        #pragma unroll
        for (int ni = 0; ni < 6; ++ni) acc1[mi][ni] = (v4f)(0.f);

    #pragma unroll
    for (int kt = 0; kt < 2; ++kt) {
        v8s a0 = *reinterpret_cast<const v8s*>(&Wb[(wid * 2 + 0) * 16 + (lane & 15)][kt * 32 + quad * 8]);
        v8s a1 = *reinterpret_cast<const v8s*>(&Wb[(wid * 2 + 1) * 16 + (lane & 15)][kt * 32 + quad * 8]);
        #pragma unroll
        for (int ni = 0; ni < 6; ++ni) {
            v8s bfr = *reinterpret_cast<const v8s*>(&Xb[ni * 16 + (lane & 15)][kt * 32 + quad * 8]);
            acc1[0][ni] = __builtin_amdgcn_mfma_f32_16x16x32_bf16(a0, bfr, acc1[0][ni], 0, 0, 0);
            acc1[1][ni] = __builtin_amdgcn_mfma_f32_16x16x32_bf16(a1, bfr, acc1[1][ni], 0, 0, 0);
        }
    }
    __syncthreads();    // staging dead; region becomes QKf/Vb (last barrier in kernel)

    // epilogue: BN; rows r<8 of each 16 -> QKf fp32 (Q rows scaled by simA*log2e); r>=8 -> Vb bf16
    #pragma unroll
    for (int mi = 0; mi < 2; ++mi) {
        const int mt = wid * 2 + mi;            // = group g
        const float sA = sim_gamma[mt] * rsqrtf(sim_var[mt] + EPS) * LOG2E;
        #pragma unroll
        for (int reg = 0; reg < 4; ++reg) {
            int o = mt * 16 + quad * 4 + reg;
            int r = o & 15;
            float sc = qkv_gamma[o] * rsqrtf(qkv_var[o] + EPS);
            float mb = qkv_beta[o] - qkv_mean[o] * sc;
            if (r < 4) { sc *= sA; mb *= sA; }
            if (r < 8) {
                #pragma unroll
                for (int ni = 0; ni < 6; ++ni)
                    QKf[mt * 8 + r][ni * 16 + (lane & 15)] = acc1[mi][ni][reg] * sc + mb;
            } else {
                #pragma unroll
                for (int ni = 0; ni < 6; ++ni)
                    Vb[mt * 8 + (r - 8)][ni * 16 + (lane & 15)] = f2bf(acc1[mi][ni][reg] * sc + mb);
            }
        }
    }
    // NO barrier: each wave consumes only rows it just wrote.

    // ---------------- Phase 2: wave-private groups, P in registers ----------------
    const int r15 = lane & 15;

    for (int gi = 0; gi < 2; ++gi) {
        const int g = wid * 2 + gi;

        // q preload: 24 broadcast b32 reads
        float qv[4][6];
        #pragma unroll
        for (int c = 0; c < 4; ++c)
            #pragma unroll
            for (int mt = 0; mt < 6; ++mt)
                qv[c][mt] = QKf[g * 8 + c][mt * 16 + r15];

        v4f acc[6];
        v4f rs4[6];
        #pragma unroll
        for (int mt = 0; mt < 6; ++mt) { acc[mt] = (v4f)(0.f); rs4[mt] = (v4f)(0.f); }

        const float* kbase = &QKf[g * 8 + 4][quad * 8];
        const unsigned short* vbase = &Vb[g * 8 + (lane & 7)][quad * 8];

        #pragma unroll
        for (int kt = 0; kt < 3; ++kt) {
            // K block for this kt: 8 b128 broadcast reads, reused across 6 m-tiles
            v4f kA[4], kB[4];
            #pragma unroll
            for (int c = 0; c < 4; ++c) {
                kA[c] = *reinterpret_cast<const v4f*>(kbase + c * 100 + kt * 32);
                kB[c] = *reinterpret_cast<const v4f*>(kbase + c * 100 + kt * 32 + 4);
            }
            v8s vf = *reinterpret_cast<const v8s*>(vbase + kt * 32);

            #pragma unroll
            for (int mt = 0; mt < 6; ++mt) {
                // vector form: backend may select v_pk_fma_f32; scalar fallback == R2
                v4f sA = (v4f)(qv[0][mt]) * kA[0];
                v4f sB = (v4f)(qv[0][mt]) * kB[0];
                #pragma unroll
                for (int c = 1; c < 4; ++c) {
                    sA += (v4f)(qv[c][mt]) * kA[c];
                    sB += (v4f)(qv[c][mt]) * kB[c];
                }
                v4f eA, eB;
                #pragma unroll
                for (int jj = 0; jj < 4; ++jj) {
                    eA[jj] = __builtin_amdgcn_exp2f(sA[jj]);
                    eB[jj] = __builtin_amdgcn_exp2f(sB[jj]);
                }
                rs4[mt] += eA + eB;
                union { unsigned u[4]; v8s v; } pf;
                pf.u[0] = cvt_pk_bf16(eA[0], eA[1]);
                pf.u[1] = cvt_pk_bf16(eA[2], eA[3]);
                pf.u[2] = cvt_pk_bf16(eB[0], eB[1]);
                pf.u[3] = cvt_pk_bf16(eB[2], eB[3]);
                acc[mt] = __builtin_amdgcn_mfma_f32_16x16x32_bf16(pf.v, vf, acc[mt], 0, 0, 0);
            }
        }

        // row denominators: horizontal + reduce across the 4 quads
        float zr[6];
        #pragma unroll
        for (int mt = 0; mt < 6; ++mt) {
            float t = (rs4[mt][0] + rs4[mt][1]) + (rs4[mt][2] + rs4[mt][3]);
            t += __shfl_xor(t, 16);
            t += __shfl_xor(t, 32);
            zr[mt] = __builtin_amdgcn_rcpf(t);
        }

        const int dd = g * 8 + (r15 & 7);
        float osc = out_gamma[dd] * rsqrtf(out_var[dd] + EPS);
        float ob  = out_beta[dd] - out_mean[dd] * osc;

        #pragma unroll
        for (int mt = 0; mt < 6; ++mt) {
            float zz[4];
            #pragma unroll
            for (int reg = 0; reg < 4; ++reg)         // all lanes active for shfl
                zz[reg] = __shfl(zr[mt], quad * 4 + reg);
            if (r15 < 8) {
                float4 o4;
                o4.x = acc[mt][0] * (zz[0] * osc) + ob;
                o4.y = acc[mt][1] * (zz[1] * osc) + ob;
                o4.z = acc[mt][2] * (zz[2] * osc) + ob;
                o4.w = acc[mt][3] * (zz[3] * osc) + ob;
                if (DIRECT) {
                    const size_t base = (size_t)nt * 393216 + (size_t)dd * 64 + hs;
                    dst[base + (size_t)(mt * 16 + quad * 4 + 0) * 4096] = o4.x;
                    dst[base + (size_t)(mt * 16 + quad * 4 + 1) * 4096] = o4.y;
                    dst[base + (size_t)(mt * 16 + quad * 4 + 2) * 4096] = o4.z;
                    dst[base + (size_t)(mt * 16 + quad * 4 + 3) * 4096] = o4.w;
                } else {
                    // ws[b][dd][i]: 8 x 64B segments per instruction (quads share lines)
                    reinterpret_cast<float4*>(dst)[(size_t)b * 1536 + dd * 24 + mt * 4 + quad] = o4;
                }
            }
        }
    }
}

// ws (nt, hs, D, cl) -> out (nt, cl, D, hs); block = (nt, D); 2048 blocks, 24.8 KB LDS -> 6 blocks/CU
__global__ __launch_bounds__(256) void transpose_kernel(const float* __restrict__ ws,
                                                        float* __restrict__ out)
{
    __shared__ float tile[64][97];
    const int blk = blockIdx.x;          // nt*64 + D
    const int nt = blk >> 6, D = blk & 63;
    const float4* ws4 = reinterpret_cast<const float4*>(ws);
    v4f* out4 = reinterpret_cast<v4f*>(out);

    #pragma unroll
    for (int it = 0; it < 6; ++it) {
        int idx = threadIdx.x + it * 256;       // 1536 float4s = 64 hs x 24 c4
        int hsr = idx / 24, c4 = idx - hsr * 24;
        float4 v = ws4[(size_t)nt * 98304 + (size_t)hsr * 1536 + D * 24 + c4];
        tile[hsr][c4 * 4 + 0] = v.x;
        tile[hsr][c4 * 4 + 1] = v.y;
        tile[hsr][c4 * 4 + 2] = v.z;
        tile[hsr][c4 * 4 + 3] = v.w;
    }
    __syncthreads();

    #pragma unroll
    for (int it = 0; it < 6; ++it) {
        int idx = threadIdx.x + it * 256;       // 1536 float4s = 96 cl x 16 h4
        int cl = idx >> 4, h4 = idx & 15;
        v4f v;
        v[0] = tile[h4 * 4 + 0][cl];
        v[1] = tile[h4 * 4 + 1][cl];
        v[2] = tile[h4 * 4 + 2][cl];
        v[3] = tile[h4 * 4 + 3][cl];
        __builtin_nontemporal_store(v, &out4[(size_t)nt * 98304 + (size_t)cl * 1024 + D * 16 + h4]);
    }
}

extern "C" void kernel_launch(void* const* d_in, const int* in_sizes, int n_in,
                              void* d_out, int out_size, void* d_ws, size_t ws_size,
                              hipStream_t stream) {
    const float* x         = (const float*)d_in[0];
    const float* w_qkv     = (const float*)d_in[1];
    const float* qkv_gamma = (const float*)d_in[2];
    const float* qkv_beta  = (const float*)d_in[3];
    const float* qkv_mean  = (const float*)d_in[4];
    const float* qkv_var   = (const float*)d_in[5];
    const float* sim_gamma = (const float*)d_in[6];
    const float* sim_beta  = (const float*)d_in[7];
    const float* sim_mean  = (const float*)d_in[8];
    const float* sim_var   = (const float*)d_in[9];
    const float* out_gamma = (const float*)d_in[10];
    const float* out_beta  = (const float*)d_in[11];
    const float* out_mean  = (const float*)d_in[12];
    const float* out_var   = (const float*)d_in[13];
    float* out = (float*)d_out;

    const size_t ws_need = (size_t)2048 * 6144 * sizeof(float);  // 50.3 MB

    if (ws_size >= ws_need) {
        float* wsb = (float*)d_ws;
        attn_kernel<false><<<2048, 256, 0, stream>>>(
            x, w_qkv, qkv_gamma, qkv_beta, qkv_mean, qkv_var,
            sim_gamma, sim_beta, sim_mean, sim_var,
            out_gamma, out_beta, out_mean, out_var, wsb);
        transpose_kernel<<<2048, 256, 0, stream>>>(wsb, out);
    } else {
        attn_kernel<true><<<2048, 256, 0, stream>>>(
            x, w_qkv, qkv_gamma, qkv_beta, qkv_mean, qkv_var,
            sim_gamma, sim_beta, sim_mean, sim_var,
            out_gamma, out_beta, out_mean, out_var, out);
    }
}